// Round 2
// baseline (399.307 us; speedup 1.0000x reference)
//
#include <hip/hip_runtime.h>
#include <stdint.h>

typedef unsigned short u16;
typedef __bf16 bf16x8 __attribute__((ext_vector_type(8)));
typedef float f32x4 __attribute__((ext_vector_type(4)));
typedef unsigned short u16x8 __attribute__((ext_vector_type(8)));
typedef unsigned short u16x4 __attribute__((ext_vector_type(4)));
typedef u16x8 u16x8_a __attribute__((may_alias));
typedef u16x4 u16x4_a __attribute__((may_alias));

#define DEV static __device__ __forceinline__

DEV u16 f2bf(float f) {
  unsigned u = __builtin_bit_cast(unsigned, f);
  u += 0x7fffu + ((u >> 16) & 1u);   // RNE
  return (u16)(u >> 16);
}
DEV bf16x8 ld8(const u16* p) {
  u16x8 v = *(const u16x8_a*)p;
  return __builtin_bit_cast(bf16x8, v);
}
DEV f32x4 vmax4(f32x4 a, f32x4 b) {
  f32x4 r;
  r[0] = fmaxf(a[0], b[0]); r[1] = fmaxf(a[1], b[1]);
  r[2] = fmaxf(a[2], b[2]); r[3] = fmaxf(a[3], b[3]);
  return r;
}
DEV f32x4 shflx4(f32x4 v, int m) {
  f32x4 r;
  r[0] = __shfl_xor(v[0], m); r[1] = __shfl_xor(v[1], m);
  r[2] = __shfl_xor(v[2], m); r[3] = __shfl_xor(v[3], m);
  return r;
}

#define GL_LDS16(gp, lp)                                                        \
  __builtin_amdgcn_global_load_lds(                                             \
      (const __attribute__((address_space(1))) void*)(gp),                      \
      (__attribute__((address_space(3))) void*)(lp), 16, 0, 0)

// ---------------- f32 -> bf16 convert ----------------
__global__ __launch_bounds__(256) void cvt_k(const float* __restrict__ s,
                                             u16* __restrict__ d, int n4) {
  int i = blockIdx.x * 256 + threadIdx.x;
  if (i < n4) {
    float4 v = ((const float4*)s)[i];
    u16x4 o;
    o[0] = f2bf(v.x); o[1] = f2bf(v.y); o[2] = f2bf(v.z); o[3] = f2bf(v.w);
    *(u16x4_a*)(d + (size_t)i * 4) = o;
  }
}

// ---------------- layernorm (f32 in, bf16 out), one row per block ----------------
__global__ __launch_bounds__(256) void ln_k(const float* __restrict__ x,
                                            const float* __restrict__ w,
                                            const float* __restrict__ b,
                                            u16* __restrict__ o) {
  const int row = blockIdx.x, t = threadIdx.x;
  const float4 v = ((const float4*)(x + (size_t)row * 1024))[t];
  float s = v.x + v.y + v.z + v.w;
  float q = v.x * v.x + v.y * v.y + v.z * v.z + v.w * v.w;
#pragma unroll
  for (int m = 1; m < 64; m <<= 1) { s += __shfl_xor(s, m); q += __shfl_xor(q, m); }
  __shared__ float ss[4], qq[4];
  if ((t & 63) == 0) { ss[t >> 6] = s; qq[t >> 6] = q; }
  __syncthreads();
  s = ss[0] + ss[1] + ss[2] + ss[3];
  q = qq[0] + qq[1] + qq[2] + qq[3];
  const float mean = s * (1.f / 1024.f);
  const float var = q * (1.f / 1024.f) - mean * mean;
  const float rstd = rsqrtf(var + 1e-5f);
  const float4 wv = ((const float4*)w)[t];
  const float4 bv = ((const float4*)b)[t];
  u16x4 ov;
  ov[0] = f2bf((v.x - mean) * rstd * wv.x + bv.x);
  ov[1] = f2bf((v.y - mean) * rstd * wv.y + bv.y);
  ov[2] = f2bf((v.z - mean) * rstd * wv.z + bv.z);
  ov[3] = f2bf((v.w - mean) * rstd * wv.w + bv.w);
  *(u16x4_a*)(o + (size_t)row * 1024 + t * 4) = ov;
}

// ---------------- GEMM: C[M,N] = A[M,K] @ Bw[N,K]^T  (m97 structure) ----------------
// EPI 0: store bf16; 1: relu -> bf16; 2: f32 out = res + acc
template <int EPI>
__global__ __launch_bounds__(256) void gemm_bt(const u16* __restrict__ A,
                                               const u16* __restrict__ Bw,
                                               void* __restrict__ Cp,
                                               const float* __restrict__ res,
                                               int M, int N, int K) {
  __shared__ __align__(16) u16 Asm[2][128 * 32];
  __shared__ __align__(16) u16 Bsm[2][128 * 32];
  const int t = threadIdx.x;
  const int l = t & 63, l15 = l & 15, l4 = l >> 4;
  const int w = t >> 6, wr = w >> 1, wc = w & 1;
  const int bm0 = blockIdx.y * 128, bn0 = blockIdx.x * 128;

  auto stage = [&](int kt, int buf) {
    const int k0 = kt * 32;
#pragma unroll
    for (int i = 0; i < 2; ++i) {
      const int s2 = t + i * 256;                       // 512 slots x 8 elts = 128x32 tile
      const u16* ga = A + (size_t)(bm0 + (s2 >> 2)) * K + k0 + (s2 & 3) * 8;
      GL_LDS16(ga, &Asm[buf][(s2 >> 6) * 512]);         // wave-uniform base + lane*16B
      const u16* gb = Bw + (size_t)(bn0 + (s2 >> 2)) * K + k0 + (s2 & 3) * 8;
      GL_LDS16(gb, &Bsm[buf][(s2 >> 6) * 512]);
    }
  };

  f32x4 acc[4][4] = {};
  stage(0, 0);
  const int nk = K >> 5;
  int cur = 0;
  for (int kt = 0; kt < nk; ++kt) {
    __syncthreads();                                    // drains vmcnt: tile[cur] ready
    if (kt + 1 < nk) stage(kt + 1, cur ^ 1);
    bf16x8 af[4], bfr[4];
#pragma unroll
    for (int m = 0; m < 4; ++m)
      af[m] = ld8(&Asm[cur][(wr * 64 + m * 16 + l15) * 32 + l4 * 8]);
#pragma unroll
    for (int n = 0; n < 4; ++n)
      bfr[n] = ld8(&Bsm[cur][(wc * 64 + n * 16 + l15) * 32 + l4 * 8]);
#pragma unroll
    for (int m = 0; m < 4; ++m)
#pragma unroll
      for (int n = 0; n < 4; ++n)
        acc[m][n] = __builtin_amdgcn_mfma_f32_16x16x32_bf16(af[m], bfr[n], acc[m][n], 0, 0, 0);
    __syncthreads();                                    // all reads of buf[cur] done
    cur ^= 1;
  }

#pragma unroll
  for (int m = 0; m < 4; ++m) {
#pragma unroll
    for (int n = 0; n < 4; ++n) {
      const int col = bn0 + wc * 64 + n * 16 + l15;
#pragma unroll
      for (int r = 0; r < 4; ++r) {
        const int row = bm0 + wr * 64 + m * 16 + l4 * 4 + r;
        const size_t idx = (size_t)row * N + col;
        float v = acc[m][n][r];
        if constexpr (EPI == 1) v = v > 0.f ? v : 0.f;
        if constexpr (EPI == 2) {
          ((float*)Cp)[idx] = res[idx] + v;
        } else {
          ((u16*)Cp)[idx] = f2bf(v);
        }
      }
    }
  }
}

// ---------------- causal flash attention, dk=64, Q-tile 64 rows, K-tile 64 ----------------
__global__ __launch_bounds__(256) void attn_k(const u16* __restrict__ Qm,
                                              const u16* __restrict__ Km,
                                              const u16* __restrict__ Vm,
                                              u16* __restrict__ Om, int ldq) {
  const int S = 2048, D = 1024;
  const int bx = blockIdx.x;                 // q-tile index
  const int bh = blockIdx.y, bb = bh >> 4, h = bh & 15;
  const int t = threadIdx.x, w = t >> 6, l = t & 63, l15 = l & 15, l4 = l >> 4;
  const int q0 = bx * 64;
  const float NEGINF = -__builtin_inff();

  __shared__ __align__(16) u16 Ksm[64][72];   // [krow][d]   pitch 72 (4-bank row shift)
  __shared__ __align__(16) u16 Vsm[64][72];   // [d][krow]   transposed
  __shared__ __align__(16) u16 Psm[4][16][72];// per-wave P tile

  const u16* Qb = Qm + (size_t)bb * S * ldq + h * 64;
  const u16* Kb = Km + (size_t)bb * S * ldq + h * 64;
  const u16* Vb = Vm + (size_t)bb * S * ldq + h * 64;

  bf16x8 qf[2];
  {
    const int qr = q0 + w * 16 + l15;
#pragma unroll
    for (int c = 0; c < 2; ++c) qf[c] = ld8(Qb + (size_t)qr * ldq + c * 32 + l4 * 8);
  }

  f32x4 acc[4] = {};
  f32x4 mrow = {NEGINF, NEGINF, NEGINF, NEGINF};
  f32x4 lrow = {};

  for (int j = 0; j <= bx; ++j) {
    const int k0 = j * 64;
    __syncthreads();                           // prior iter's K/V reads done
#pragma unroll
    for (int i = 0; i < 2; ++i) {
      const int s2 = t + i * 256;
      const int kr = s2 >> 3, c0 = (s2 & 7) * 8;
      u16x8 kv = *(const u16x8_a*)(Kb + (size_t)(k0 + kr) * ldq + c0);
      *(u16x8_a*)&Ksm[kr][c0] = kv;
      u16x8 vv = *(const u16x8_a*)(Vb + (size_t)(k0 + kr) * ldq + c0);
#pragma unroll
      for (int e = 0; e < 8; ++e) Vsm[c0 + e][kr] = vv[e];   // transpose scatter
    }
    __syncthreads();

    // S = Q @ K^T
    f32x4 sv[4] = {};
#pragma unroll
    for (int c = 0; c < 2; ++c) {
#pragma unroll
      for (int nf = 0; nf < 4; ++nf) {
        bf16x8 kf = ld8(&Ksm[nf * 16 + l15][c * 32 + l4 * 8]);
        sv[nf] = __builtin_amdgcn_mfma_f32_16x16x32_bf16(qf[c], kf, sv[nf], 0, 0, 0);
      }
    }
#pragma unroll
    for (int nf = 0; nf < 4; ++nf) sv[nf] *= 0.125f;   // 1/sqrt(64)

    if (j == bx) {                                     // causal mask, diagonal tile only
#pragma unroll
      for (int nf = 0; nf < 4; ++nf) {
        const int col = k0 + nf * 16 + l15;
#pragma unroll
        for (int r = 0; r < 4; ++r) {
          const int rowq = q0 + w * 16 + l4 * 4 + r;
          if (col > rowq) sv[nf][r] = NEGINF;
        }
      }
    }

    // online softmax: row stats live per (l4-group, r)
    f32x4 mt = vmax4(vmax4(sv[0], sv[1]), vmax4(sv[2], sv[3]));
#pragma unroll
    for (int msk = 1; msk < 16; msk <<= 1) mt = vmax4(mt, shflx4(mt, msk));
    const f32x4 mnew = vmax4(mrow, mt);
    f32x4 sf;
    f32x4 psum = {};
#pragma unroll
    for (int r = 0; r < 4; ++r) sf[r] = __expf(mrow[r] - mnew[r]);
#pragma unroll
    for (int nf = 0; nf < 4; ++nf) {
#pragma unroll
      for (int r = 0; r < 4; ++r) {
        const float p = __expf(sv[nf][r] - mnew[r]);
        sv[nf][r] = p;
        psum[r] += p;
      }
    }
#pragma unroll
    for (int msk = 1; msk < 16; msk <<= 1) psum += shflx4(psum, msk);
#pragma unroll
    for (int r = 0; r < 4; ++r) lrow[r] = lrow[r] * sf[r] + psum[r];
#pragma unroll
    for (int nf = 0; nf < 4; ++nf) acc[nf] *= sf;
    mrow = mnew;

    // P -> per-wave LDS (layout fix: C-layout -> A-layout)
#pragma unroll
    for (int nf = 0; nf < 4; ++nf)
#pragma unroll
      for (int r = 0; r < 4; ++r)
        Psm[w][l4 * 4 + r][nf * 16 + l15] = f2bf(sv[nf][r]);

    // O += P @ V
#pragma unroll
    for (int c = 0; c < 2; ++c) {
      bf16x8 pf = ld8(&Psm[w][l15][c * 32 + l4 * 8]);
#pragma unroll
      for (int nf = 0; nf < 4; ++nf) {
        bf16x8 vf = ld8(&Vsm[nf * 16 + l15][c * 32 + l4 * 8]);
        acc[nf] = __builtin_amdgcn_mfma_f32_16x16x32_bf16(pf, vf, acc[nf], 0, 0, 0);
      }
    }
  }

#pragma unroll
  for (int nf = 0; nf < 4; ++nf) {
    const int col = h * 64 + nf * 16 + l15;
#pragma unroll
    for (int r = 0; r < 4; ++r) {
      const int rowq = q0 + w * 16 + l4 * 4 + r;
      Om[((size_t)bb * S + rowq) * D + col] = f2bf(acc[nf][r] / lrow[r]);
    }
  }
}

// ---------------- orchestration ----------------
extern "C" void kernel_launch(void* const* d_in, const int* in_sizes, int n_in,
                              void* d_out, int out_size, void* d_ws, size_t ws_size,
                              hipStream_t stream) {
  (void)in_sizes; (void)n_in; (void)out_size; (void)ws_size;
  const float* x    = (const float*)d_in[0];
  const float* W_q  = (const float*)d_in[1];
  const float* W_k  = (const float*)d_in[2];
  const float* W_v  = (const float*)d_in[3];
  const float* W_o  = (const float*)d_in[4];
  const float* W1   = (const float*)d_in[5];
  const float* W2   = (const float*)d_in[6];
  const float* ln1w = (const float*)d_in[7];
  const float* ln1b = (const float*)d_in[8];
  const float* ln2w = (const float*)d_in[9];
  const float* ln2b = (const float*)d_in[10];

  const size_t MB = 1ull << 20;
  char* W = (char*)d_ws;
  u16* wqkv  = (u16*)(W + 0);        //  6 MB  packed [3072][1024] bf16
  u16* wo    = (u16*)(W + 6 * MB);   //  2 MB
  u16* w1b   = (u16*)(W + 8 * MB);   //  8 MB
  u16* w2b   = (u16*)(W + 16 * MB);  //  8 MB
  u16* xn1   = (u16*)(W + 24 * MB);  //  8 MB
  u16* qkv   = (u16*)(W + 32 * MB);  // 24 MB  [4096][3072] bf16
  u16* attnb = (u16*)(W + 56 * MB);  //  8 MB  [4096][1024] bf16
  u16* xn2   = (u16*)(W + 64 * MB);  //  8 MB  -> peak ws = 72 MB
  u16* hbuf  = (u16*)(W + 24 * MB);  // 32 MB, reuses dead xn1+qkv region
  float* x2  = (float*)d_out;        // residual stream lives in d_out

  auto cvt = [&](const float* s, u16* d, int n) {
    int n4 = n >> 2;
    cvt_k<<<dim3((n4 + 255) / 256), dim3(256), 0, stream>>>(s, d, n4);
  };
  cvt(W_q, wqkv, 1 << 20);
  cvt(W_k, wqkv + (1 << 20), 1 << 20);
  cvt(W_v, wqkv + (2 << 20), 1 << 20);
  cvt(W_o, wo, 1 << 20);
  cvt(W1, w1b, 4 << 20);
  cvt(W2, w2b, 4 << 20);

  // x -> LN1 -> xn1
  ln_k<<<dim3(4096), dim3(256), 0, stream>>>(x, ln1w, ln1b, xn1);
  // fused QKV projection
  gemm_bt<0><<<dim3(24, 32), dim3(256), 0, stream>>>(xn1, wqkv, qkv, nullptr, 4096, 3072, 1024);
  // causal flash attention
  attn_k<<<dim3(32, 32), dim3(256), 0, stream>>>(qkv, qkv + 1024, qkv + 2048, attnb, 3072);
  // x2 = x + attn @ Wo^T   (written into d_out)
  gemm_bt<2><<<dim3(8, 32), dim3(256), 0, stream>>>(attnb, wo, x2, x, 4096, 1024, 1024);
  // LN2
  ln_k<<<dim3(4096), dim3(256), 0, stream>>>(x2, ln2w, ln2b, xn2);
  // h = relu(xn2 @ W1^T)
  gemm_bt<1><<<dim3(32, 32), dim3(256), 0, stream>>>(xn2, w1b, hbuf, nullptr, 4096, 4096, 1024);
  // out = x2 + h @ W2^T  (in-place read-then-write per element on d_out)
  gemm_bt<2><<<dim3(8, 32), dim3(256), 0, stream>>>(hbuf, w2b, (void*)x2, x2, 4096, 1024, 4096);
}

// Round 3
// 289.462 us; speedup vs baseline: 1.3795x; 1.3795x over previous
//
#include <hip/hip_runtime.h>
#include <stdint.h>

typedef unsigned short u16;
typedef __bf16 bf16x8 __attribute__((ext_vector_type(8)));
typedef float f32x4 __attribute__((ext_vector_type(4)));
typedef unsigned short u16x8 __attribute__((ext_vector_type(8)));
typedef unsigned short u16x4 __attribute__((ext_vector_type(4)));
typedef u16x8 u16x8_a __attribute__((may_alias));
typedef u16x4 u16x4_a __attribute__((may_alias));

#define DEV static __device__ __forceinline__

DEV u16 f2bf(float f) {
  unsigned u = __builtin_bit_cast(unsigned, f);
  u += 0x7fffu + ((u >> 16) & 1u);   // RNE
  return (u16)(u >> 16);
}
DEV bf16x8 ld8(const u16* p) {
  u16x8 v = *(const u16x8_a*)p;
  return __builtin_bit_cast(bf16x8, v);
}
DEV f32x4 vmax4(f32x4 a, f32x4 b) {
  f32x4 r;
  r[0] = fmaxf(a[0], b[0]); r[1] = fmaxf(a[1], b[1]);
  r[2] = fmaxf(a[2], b[2]); r[3] = fmaxf(a[3], b[3]);
  return r;
}
DEV f32x4 shflx4(f32x4 v, int m) {
  f32x4 r;
  r[0] = __shfl_xor(v[0], m); r[1] = __shfl_xor(v[1], m);
  r[2] = __shfl_xor(v[2], m); r[3] = __shfl_xor(v[3], m);
  return r;
}

#define GL_LDS16(gp, lp)                                                        \
  __builtin_amdgcn_global_load_lds(                                             \
      (const __attribute__((address_space(1))) void*)(gp),                      \
      (__attribute__((address_space(3))) void*)(lp), 16, 0, 0)

// ---------------- f32 -> bf16 convert ----------------
__global__ __launch_bounds__(256) void cvt_k(const float* __restrict__ s,
                                             u16* __restrict__ d, int n4) {
  int i = blockIdx.x * 256 + threadIdx.x;
  if (i < n4) {
    float4 v = ((const float4*)s)[i];
    u16x4 o;
    o[0] = f2bf(v.x); o[1] = f2bf(v.y); o[2] = f2bf(v.z); o[3] = f2bf(v.w);
    *(u16x4_a*)(d + (size_t)i * 4) = o;
  }
}

// ---------------- layernorm (f32 in, bf16 out), one row per block ----------------
__global__ __launch_bounds__(256) void ln_k(const float* __restrict__ x,
                                            const float* __restrict__ w,
                                            const float* __restrict__ b,
                                            u16* __restrict__ o) {
  const int row = blockIdx.x, t = threadIdx.x;
  const float4 v = ((const float4*)(x + (size_t)row * 1024))[t];
  float s = v.x + v.y + v.z + v.w;
  float q = v.x * v.x + v.y * v.y + v.z * v.z + v.w * v.w;
#pragma unroll
  for (int m = 1; m < 64; m <<= 1) { s += __shfl_xor(s, m); q += __shfl_xor(q, m); }
  __shared__ float ss[4], qq[4];
  if ((t & 63) == 0) { ss[t >> 6] = s; qq[t >> 6] = q; }
  __syncthreads();
  s = ss[0] + ss[1] + ss[2] + ss[3];
  q = qq[0] + qq[1] + qq[2] + qq[3];
  const float mean = s * (1.f / 1024.f);
  const float var = q * (1.f / 1024.f) - mean * mean;
  const float rstd = rsqrtf(var + 1e-5f);
  const float4 wv = ((const float4*)w)[t];
  const float4 bv = ((const float4*)b)[t];
  u16x4 ov;
  ov[0] = f2bf((v.x - mean) * rstd * wv.x + bv.x);
  ov[1] = f2bf((v.y - mean) * rstd * wv.y + bv.y);
  ov[2] = f2bf((v.z - mean) * rstd * wv.z + bv.z);
  ov[3] = f2bf((v.w - mean) * rstd * wv.w + bv.w);
  *(u16x4_a*)(o + (size_t)row * 1024 + t * 4) = ov;
}

// ---------------- V transpose: qkv V-section [b,s,h,d] -> vt[(b,h),d,s] ----------------
__global__ __launch_bounds__(256) void vtr_k(const u16* __restrict__ qkvV,
                                             u16* __restrict__ vt) {
  __shared__ u16 T[64][65];
  const int st = blockIdx.x, bh = blockIdx.y;
  const int b = bh >> 4, h = bh & 15;
  const int t = threadIdx.x;
  const u16* src = qkvV + ((size_t)(b * 2048 + st * 64)) * 3072 + h * 64;
  const int r = t >> 2, c0 = (t & 3) * 16;
  u16x8 a0 = *(const u16x8_a*)(src + (size_t)r * 3072 + c0);
  u16x8 a1 = *(const u16x8_a*)(src + (size_t)r * 3072 + c0 + 8);
#pragma unroll
  for (int e = 0; e < 8; ++e) { T[r][c0 + e] = a0[e]; T[r][c0 + 8 + e] = a1[e]; }
  __syncthreads();
  const int d = t >> 2, s0 = (t & 3) * 16;
  u16x8 o0, o1;
#pragma unroll
  for (int e = 0; e < 8; ++e) { o0[e] = T[s0 + e][d]; o1[e] = T[s0 + 8 + e][d]; }
  u16* dst = vt + ((size_t)bh * 64 + d) * 2048 + (size_t)st * 64 + s0;
  *(u16x8_a*)dst = o0;
  *(u16x8_a*)(dst + 8) = o1;
}

// ---------------- GEMM: C[M,N] = A[M,K] @ Bw[N,K]^T  (m97 structure) ----------------
// EPI 0: store bf16; 1: relu -> bf16; 2: f32 out = res + acc
template <int EPI, int BM>
__global__ __launch_bounds__(256) void gemm_bt(const u16* __restrict__ A,
                                               const u16* __restrict__ Bw,
                                               void* __restrict__ Cp,
                                               const float* __restrict__ res,
                                               int M, int N, int K) {
  __shared__ __align__(16) u16 Asm[2][BM * 32];
  __shared__ __align__(16) u16 Bsm[2][128 * 32];
  const int t = threadIdx.x;
  const int l = t & 63, l15 = l & 15, l4 = l >> 4;
  const int w = t >> 6, wr = w >> 1, wc = w & 1;
  const int bm0 = blockIdx.y * BM, bn0 = blockIdx.x * 128;
  constexpr int MR = BM / 32;   // m-fragments per wave

  auto stage = [&](int kt, int buf) {
    const int k0 = kt * 32;
#pragma unroll
    for (int i = 0; i < BM / 64; ++i) {
      const int s2 = t + i * 256;
      const u16* ga = A + (size_t)(bm0 + (s2 >> 2)) * K + k0 + (s2 & 3) * 8;
      GL_LDS16(ga, &Asm[buf][(s2 >> 6) * 512]);
    }
#pragma unroll
    for (int i = 0; i < 2; ++i) {
      const int s2 = t + i * 256;
      const u16* gb = Bw + (size_t)(bn0 + (s2 >> 2)) * K + k0 + (s2 & 3) * 8;
      GL_LDS16(gb, &Bsm[buf][(s2 >> 6) * 512]);
    }
  };

  f32x4 acc[MR][4] = {};
  stage(0, 0);
  const int nk = K >> 5;
  int cur = 0;
  for (int kt = 0; kt < nk; ++kt) {
    __syncthreads();                                    // drains vmcnt: tile[cur] ready
    if (kt + 1 < nk) stage(kt + 1, cur ^ 1);
    bf16x8 af[MR], bfr[4];
#pragma unroll
    for (int m = 0; m < MR; ++m)
      af[m] = ld8(&Asm[cur][(wr * (BM / 2) + m * 16 + l15) * 32 + l4 * 8]);
#pragma unroll
    for (int n = 0; n < 4; ++n)
      bfr[n] = ld8(&Bsm[cur][(wc * 64 + n * 16 + l15) * 32 + l4 * 8]);
#pragma unroll
    for (int m = 0; m < MR; ++m)
#pragma unroll
      for (int n = 0; n < 4; ++n)
        acc[m][n] = __builtin_amdgcn_mfma_f32_16x16x32_bf16(af[m], bfr[n], acc[m][n], 0, 0, 0);
    __syncthreads();                                    // all reads of buf[cur] done
    cur ^= 1;
  }

#pragma unroll
  for (int m = 0; m < MR; ++m) {
#pragma unroll
    for (int n = 0; n < 4; ++n) {
      const int col = bn0 + wc * 64 + n * 16 + l15;
#pragma unroll
      for (int r = 0; r < 4; ++r) {
        const int row = bm0 + wr * (BM / 2) + m * 16 + l4 * 4 + r;
        const size_t idx = (size_t)row * N + col;
        float v = acc[m][n][r];
        if constexpr (EPI == 1) v = v > 0.f ? v : 0.f;
        if constexpr (EPI == 2) {
          ((float*)Cp)[idx] = res[idx] + v;
        } else {
          ((u16*)Cp)[idx] = f2bf(v);
        }
      }
    }
  }
}

// ---------------- causal flash attention v2 ----------------
// grid (16, B*H); block handles q-tiles p and 31-p (balanced: 33 iters each).
// K and V^T staged via global_load_lds into XOR-swizzled linear [64][64] LDS.
__global__ __launch_bounds__(256) void attn_k(const u16* __restrict__ Qm,
                                              const u16* __restrict__ Km,
                                              const u16* __restrict__ vt,
                                              u16* __restrict__ Om) {
  const int S = 2048, D = 1024, ldq = 3072;
  const int p = blockIdx.x;
  const int bh = blockIdx.y, bb = bh >> 4, h = bh & 15;
  const int t = threadIdx.x, w = t >> 6, l = t & 63, l15 = l & 15, l4 = l >> 4;
  const float NEGINF = -__builtin_inff();

  __shared__ __align__(16) u16 Ksm[2][64 * 64];   // [krow][d], XOR-swizzled
  __shared__ __align__(16) u16 Vsm[2][64 * 64];   // [d][krow], XOR-swizzled (from vt)
  __shared__ __align__(16) u16 Psm[4][16][72];    // per-wave P tile

  const u16* Qb = Qm + (size_t)bb * S * ldq + h * 64;
  const u16* Kb = Km + (size_t)bb * S * ldq + h * 64;
  const u16* Vtb = vt + (size_t)bh * 64 * 2048;

  auto stageKV = [&](int j, int buf) {
    const int k0 = j * 64;
#pragma unroll
    for (int i = 0; i < 2; ++i) {
      const int s = t + i * 256;                 // slot 0..511 (16B each)
      const int row = s >> 3;
      const int colE = ((s & 7) ^ (row & 7)) * 8; // inverse-swizzled source column
      GL_LDS16(Kb + (size_t)(k0 + row) * ldq + colE, &Ksm[buf][(s >> 6) * 512]);
      GL_LDS16(Vtb + (size_t)row * 2048 + k0 + colE, &Vsm[buf][(s >> 6) * 512]);
    }
  };

  for (int half = 0; half < 2; ++half) {
    const int bx = half ? (31 - p) : p;
    const int q0 = bx * 64;
    __syncthreads();                             // prev half's LDS reads done
    stageKV(0, 0);

    bf16x8 qf[2];
    {
      const int qr = q0 + w * 16 + l15;
#pragma unroll
      for (int c = 0; c < 2; ++c) qf[c] = ld8(Qb + (size_t)qr * ldq + c * 32 + l4 * 8);
    }

    f32x4 acc[4] = {};
    f32x4 mrow = {NEGINF, NEGINF, NEGINF, NEGINF};
    f32x4 lrow = {};
    int cur = 0;

    for (int j = 0; j <= bx; ++j) {
      __syncthreads();                           // buf[cur] staged (vmcnt drained)
      if (j < bx) stageKV(j + 1, cur ^ 1);       // prefetch next tile

      // S = Q @ K^T
      f32x4 sv[4] = {};
#pragma unroll
      for (int c = 0; c < 2; ++c) {
#pragma unroll
        for (int nf = 0; nf < 4; ++nf) {
          const int row = nf * 16 + l15;
          bf16x8 kf = ld8(&Ksm[cur][row * 64 + ((c * 32 + l4 * 8) ^ ((row & 7) * 8))]);
          sv[nf] = __builtin_amdgcn_mfma_f32_16x16x32_bf16(qf[c], kf, sv[nf], 0, 0, 0);
        }
      }
#pragma unroll
      for (int nf = 0; nf < 4; ++nf) sv[nf] *= 0.125f;   // 1/sqrt(64)

      if (j == bx) {                             // causal mask, diagonal tile only
        const int k0 = j * 64;
#pragma unroll
        for (int nf = 0; nf < 4; ++nf) {
          const int col = k0 + nf * 16 + l15;
#pragma unroll
          for (int r = 0; r < 4; ++r) {
            const int rowq = q0 + w * 16 + l4 * 4 + r;
            if (col > rowq) sv[nf][r] = NEGINF;
          }
        }
      }

      // online softmax (row stats per (l4-group, r), reduced over 16 lanes)
      f32x4 mt = vmax4(vmax4(sv[0], sv[1]), vmax4(sv[2], sv[3]));
#pragma unroll
      for (int msk = 1; msk < 16; msk <<= 1) mt = vmax4(mt, shflx4(mt, msk));
      const f32x4 mnew = vmax4(mrow, mt);
      f32x4 sf;
      f32x4 psum = {};
#pragma unroll
      for (int r = 0; r < 4; ++r) sf[r] = __expf(mrow[r] - mnew[r]);
#pragma unroll
      for (int nf = 0; nf < 4; ++nf) {
#pragma unroll
        for (int r = 0; r < 4; ++r) {
          const float pv = __expf(sv[nf][r] - mnew[r]);
          sv[nf][r] = pv;
          psum[r] += pv;
        }
      }
#pragma unroll
      for (int msk = 1; msk < 16; msk <<= 1) psum += shflx4(psum, msk);
#pragma unroll
      for (int r = 0; r < 4; ++r) lrow[r] = lrow[r] * sf[r] + psum[r];
#pragma unroll
      for (int nf = 0; nf < 4; ++nf) acc[nf] *= sf;
      mrow = mnew;

      // P -> per-wave LDS (C-layout -> A-layout)
#pragma unroll
      for (int nf = 0; nf < 4; ++nf)
#pragma unroll
        for (int r = 0; r < 4; ++r)
          Psm[w][l4 * 4 + r][nf * 16 + l15] = f2bf(sv[nf][r]);

      // O += P @ V
#pragma unroll
      for (int c = 0; c < 2; ++c) {
        bf16x8 pf = ld8(&Psm[w][l15][c * 32 + l4 * 8]);
#pragma unroll
        for (int nf = 0; nf < 4; ++nf) {
          const int row = nf * 16 + l15;
          bf16x8 vf = ld8(&Vsm[cur][row * 64 + ((c * 32 + l4 * 8) ^ ((row & 7) * 8))]);
          acc[nf] = __builtin_amdgcn_mfma_f32_16x16x32_bf16(pf, vf, acc[nf], 0, 0, 0);
        }
      }
      cur ^= 1;
    }

#pragma unroll
    for (int nf = 0; nf < 4; ++nf) {
      const int col = h * 64 + nf * 16 + l15;
#pragma unroll
      for (int r = 0; r < 4; ++r) {
        const int rowq = q0 + w * 16 + l4 * 4 + r;
        Om[((size_t)bb * S + rowq) * D + col] = f2bf(acc[nf][r] / lrow[r]);
      }
    }
  }
}

// ---------------- orchestration ----------------
extern "C" void kernel_launch(void* const* d_in, const int* in_sizes, int n_in,
                              void* d_out, int out_size, void* d_ws, size_t ws_size,
                              hipStream_t stream) {
  (void)in_sizes; (void)n_in; (void)out_size; (void)ws_size;
  const float* x    = (const float*)d_in[0];
  const float* W_q  = (const float*)d_in[1];
  const float* W_k  = (const float*)d_in[2];
  const float* W_v  = (const float*)d_in[3];
  const float* W_o  = (const float*)d_in[4];
  const float* W1   = (const float*)d_in[5];
  const float* W2   = (const float*)d_in[6];
  const float* ln1w = (const float*)d_in[7];
  const float* ln1b = (const float*)d_in[8];
  const float* ln2w = (const float*)d_in[9];
  const float* ln2b = (const float*)d_in[10];

  const size_t MB = 1ull << 20;
  char* W = (char*)d_ws;
  u16* wqkv  = (u16*)(W + 0);        //  6 MB  packed [3072][1024] bf16
  u16* wo    = (u16*)(W + 6 * MB);   //  2 MB
  u16* w1b   = (u16*)(W + 8 * MB);   //  8 MB
  u16* w2b   = (u16*)(W + 16 * MB);  //  8 MB
  u16* xn1   = (u16*)(W + 24 * MB);  //  8 MB
  u16* qkv   = (u16*)(W + 32 * MB);  // 24 MB  [4096][3072] bf16
  u16* attnb = (u16*)(W + 56 * MB);  //  8 MB  [4096][1024] bf16
  u16* vt    = (u16*)(W + 64 * MB);  //  8 MB  V^T [(b,h),64,2048]; dead after attn
  u16* xn2   = (u16*)(W + 64 * MB);  //  8 MB  written after attn (shares with vt)
  u16* hbuf  = (u16*)(W + 24 * MB);  // 32 MB, reuses dead xn1+qkv region
  float* x2  = (float*)d_out;        // residual stream lives in d_out

  auto cvt = [&](const float* s, u16* d, int n) {
    int n4 = n >> 2;
    cvt_k<<<dim3((n4 + 255) / 256), dim3(256), 0, stream>>>(s, d, n4);
  };
  cvt(W_q, wqkv, 1 << 20);
  cvt(W_k, wqkv + (1 << 20), 1 << 20);
  cvt(W_v, wqkv + (2 << 20), 1 << 20);
  cvt(W_o, wo, 1 << 20);
  cvt(W1, w1b, 4 << 20);
  cvt(W2, w2b, 4 << 20);

  // x -> LN1 -> xn1
  ln_k<<<dim3(4096), dim3(256), 0, stream>>>(x, ln1w, ln1b, xn1);
  // fused QKV projection
  gemm_bt<0, 128><<<dim3(24, 32), dim3(256), 0, stream>>>(xn1, wqkv, qkv, nullptr, 4096, 3072, 1024);
  // V transpose for attention's B-operand
  vtr_k<<<dim3(32, 32), dim3(256), 0, stream>>>(qkv + 2048, vt);
  // causal flash attention (balanced two-tile blocks)
  attn_k<<<dim3(16, 32), dim3(256), 0, stream>>>(qkv, qkv + 1024, vt, attnb);
  // x2 = x + attn @ Wo^T   (written into d_out)
  gemm_bt<2, 64><<<dim3(8, 64), dim3(256), 0, stream>>>(attnb, wo, x2, x, 4096, 1024, 1024);
  // LN2
  ln_k<<<dim3(4096), dim3(256), 0, stream>>>(x2, ln2w, ln2b, xn2);
  // h = relu(xn2 @ W1^T)
  gemm_bt<1, 128><<<dim3(32, 32), dim3(256), 0, stream>>>(xn2, w1b, hbuf, nullptr, 4096, 4096, 1024);
  // out = x2 + h @ W2^T  (in-place read-then-write per element on d_out)
  gemm_bt<2, 64><<<dim3(8, 64), dim3(256), 0, stream>>>(hbuf, w2b, (void*)x2, x2, 4096, 1024, 4096);
}